// Round 2
// baseline (1632.204 us; speedup 1.0000x reference)
//
#include <hip/hip_runtime.h>
#include <hip/hip_bf16.h>

#define HH 1080
#define WW 1920
#define HWSZ (HH * WW)

__device__ __forceinline__ float clipf(float x, float lo, float hi) {
    return fminf(fmaxf(x, lo), hi);
}

// ---------------------------------------------------------------------------
// Kernel 1: classical color grade + 3D LUT trilinear + blend -> x_blended (f32)
// ---------------------------------------------------------------------------
__global__ __launch_bounds__(256) void grade_kernel(
    const float* __restrict__ x, const float* __restrict__ lut,
    const float* __restrict__ cm, const float* __restrict__ cbp,
    const float* __restrict__ shp, const float* __restrict__ mip,
    const float* __restrict__ hip_, const float* __restrict__ cop,
    const float* __restrict__ satp, const float* __restrict__ wap,
    const float* __restrict__ lbp, float* __restrict__ xb)
{
    int i = blockIdx.x * blockDim.x + threadIdx.x;
    if (i >= HWSZ) return;

    float in0 = x[i], in1 = x[HWSZ + i], in2 = x[2 * HWSZ + i];

    float M00 = clipf(cm[0], 0.9f, 1.1f), M01 = clipf(cm[1], 0.9f, 1.1f), M02 = clipf(cm[2], 0.9f, 1.1f);
    float M10 = clipf(cm[3], 0.9f, 1.1f), M11 = clipf(cm[4], 0.9f, 1.1f), M12 = clipf(cm[5], 0.9f, 1.1f);
    float M20 = clipf(cm[6], 0.9f, 1.1f), M21 = clipf(cm[7], 0.9f, 1.1f), M22 = clipf(cm[8], 0.9f, 1.1f);
    float bi0 = clipf(cbp[0], -0.02f, 0.02f);
    float bi1 = clipf(cbp[1], -0.02f, 0.02f);
    float bi2 = clipf(cbp[2], -0.02f, 0.02f);

    float sh  = clipf(shp[0], -0.02f, 0.05f);
    float mi  = clipf(mip[0], 0.95f, 1.05f);
    float hi  = clipf(hip_[0], 0.95f, 1.05f);
    float co  = clipf(cop[0], 0.98f, 1.05f);
    float sat = clipf(satp[0], 0.95f, 1.3f);
    float wa  = clipf(wap[0], -0.02f, 0.05f);
    float lb  = clipf(lbp[0], 0.7f, 0.9f);

    float xc[3];
    xc[0] = M00 * in0 + M01 * in1 + M02 * in2 + bi0;
    xc[1] = M10 * in0 + M11 * in1 + M12 * in2 + bi1;
    xc[2] = M20 * in0 + M21 * in1 + M22 * in2 + bi2;

    float inv_mi = 1.0f / mi, inv_co = 1.0f / co;
    float xg[3];
#pragma unroll
    for (int c = 0; c < 3; c++) {
        float v = xc[c];
        float sm = clipf(1.f - v, 0.f, 1.f);
        sm = sm * sm * sm;
        float xs = v + sh * sm * (1.f - v) * 0.5f;
        float xm = powf(clipf(xs, 1e-7f, 1.f), inv_mi);
        float hm = clipf(xm, 0.f, 1.f);
        hm = hm * hm * hm;
        float x2 = clipf(xm * (1.f - hm * (1.f - hi) * 0.5f), 0.f, 1.f);
        xg[c] = powf(clipf(x2, 1e-7f, 1.f), inv_co);
    }

    float luma = 0.299f * xg[0] + 0.587f * xg[1] + 0.114f * xg[2];
    float s0 = luma + sat * (xg[0] - luma);
    float s1 = luma + sat * (xg[1] - luma);
    float s2 = luma + sat * (xg[2] - luma);

    float pr = clipf(s0 * (1.f + wa), 0.f, 1.f);
    float pg = clipf(s1 * (1.f + wa * 0.3f), 0.f, 1.f);
    float pb = clipf(s2 * (1.f - wa * 0.5f), 0.f, 1.f);

    // 3D LUT trilinear (L=33). coords = p * 32
    float cr = pr * 32.f, cg = pg * 32.f, cb2 = pb * 32.f;
    float fr = floorf(cr), fgq = floorf(cg), fb = floorf(cb2);
    float fx = cr - fr, fy = cg - fgq, fz = cb2 - fb;
    int x0 = min(max((int)fr, 0), 31);
    int y0 = min(max((int)fgq, 0), 31);
    int z0 = min(max((int)fb, 0), 31);

    const float* base = lut + ((x0 * 33 + y0) * 33 + z0) * 3;
    // strides in floats: x:+3267, y:+99, z:+3
    float pcl[3] = {pr, pg, pb};
#pragma unroll
    for (int ch = 0; ch < 3; ch++) {
        float c000 = base[ch];
        float c001 = base[3 + ch];
        float c010 = base[99 + ch];
        float c011 = base[102 + ch];
        float c100 = base[3267 + ch];
        float c101 = base[3270 + ch];
        float c110 = base[3366 + ch];
        float c111 = base[3369 + ch];
        float c00 = c000 * (1.f - fx) + c100 * fx;
        float c01 = c001 * (1.f - fx) + c101 * fx;
        float c10 = c010 * (1.f - fx) + c110 * fx;
        float c11 = c011 * (1.f - fx) + c111 * fx;
        float c0 = c00 * (1.f - fy) + c10 * fy;
        float c1 = c01 * (1.f - fy) + c11 * fy;
        float lv = c0 * (1.f - fz) + c1 * fz;
        xb[ch * HWSZ + i] = lb * lv + (1.f - lb) * pcl[ch];
    }
}

// ---------------------------------------------------------------------------
// conv1 6->32 (+BN+ReLU). Inputs: x and xb, both full-image planar f32.
// Writes rows [out_y0, out_y0+out_rows) of a bf16 buffer (channel stride
// out_rows*WW, row 0 of buffer = global row out_y0).
// ---------------------------------------------------------------------------
__global__ __launch_bounds__(256) void conv1_kernel(
    const float* __restrict__ x, const float* __restrict__ xb,
    const float* __restrict__ w,
    const float* __restrict__ bg, const float* __restrict__ bb,
    const float* __restrict__ bm, const float* __restrict__ bv,
    __hip_bfloat16* __restrict__ out, int out_y0, int out_rows)
{
    int i = blockIdx.x * blockDim.x + threadIdx.x;
    if (i >= out_rows * WW) return;
    int ly = i / WW;
    int xx = i - ly * WW;
    int y = out_y0 + ly;
    bool yl = y > 0, yh = y < HH - 1, xl = xx > 0, xh = xx < WW - 1;

    float acc[32];
#pragma unroll
    for (int c = 0; c < 32; c++) acc[c] = 0.f;

#pragma unroll 1
    for (int ci = 0; ci < 6; ci++) {
        const float* p = (ci < 3 ? x + (size_t)ci * HWSZ : xb + (size_t)(ci - 3) * HWSZ)
                         + (size_t)y * WW + xx;
        float v0 = (yl && xl) ? p[-WW - 1] : 0.f;
        float v1 = yl ? p[-WW] : 0.f;
        float v2 = (yl && xh) ? p[-WW + 1] : 0.f;
        float v3 = xl ? p[-1] : 0.f;
        float v4 = p[0];
        float v5 = xh ? p[1] : 0.f;
        float v6 = (yh && xl) ? p[WW - 1] : 0.f;
        float v7 = yh ? p[WW] : 0.f;
        float v8 = (yh && xh) ? p[WW + 1] : 0.f;
#pragma unroll
        for (int c2 = 0; c2 < 32; c2++) {
            const float* wq = w + (c2 * 6 + ci) * 9;
            acc[c2] = fmaf(v0, wq[0], acc[c2]);
            acc[c2] = fmaf(v1, wq[1], acc[c2]);
            acc[c2] = fmaf(v2, wq[2], acc[c2]);
            acc[c2] = fmaf(v3, wq[3], acc[c2]);
            acc[c2] = fmaf(v4, wq[4], acc[c2]);
            acc[c2] = fmaf(v5, wq[5], acc[c2]);
            acc[c2] = fmaf(v6, wq[6], acc[c2]);
            acc[c2] = fmaf(v7, wq[7], acc[c2]);
            acc[c2] = fmaf(v8, wq[8], acc[c2]);
        }
    }
#pragma unroll
    for (int c = 0; c < 32; c++) {
        float sc = bg[c] * rsqrtf(bv[c] + 1e-5f);
        float of = bb[c] - bm[c] * sc;
        float r = fmaxf(fmaf(acc[c], sc, of), 0.f);
        out[(size_t)c * out_rows * WW + i] = __float2bfloat16(r);
    }
}

// ---------------------------------------------------------------------------
// Generic conv CIN->COUT (+BN+ReLU), bf16 in/out, row-windowed buffers.
// in buffer holds global rows [in_y0, in_y0+in_rows), channel stride in_rows*WW.
// out buffer holds global rows [out_y0, out_y0+out_rows).
// ---------------------------------------------------------------------------
template <int CIN, int COUT>
__global__ __launch_bounds__(256) void conv_bn_relu_bf16(
    const __hip_bfloat16* __restrict__ in, int in_y0, int in_rows,
    const float* __restrict__ w,
    const float* __restrict__ bg, const float* __restrict__ bb,
    const float* __restrict__ bm, const float* __restrict__ bv,
    __hip_bfloat16* __restrict__ out, int out_y0, int out_rows)
{
    int i = blockIdx.x * blockDim.x + threadIdx.x;
    if (i >= out_rows * WW) return;
    int ly = i / WW;
    int xx = i - ly * WW;
    int y = out_y0 + ly;
    bool yl = y > 0, yh = y < HH - 1, xl = xx > 0, xh = xx < WW - 1;

    float acc[COUT];
#pragma unroll
    for (int c = 0; c < COUT; c++) acc[c] = 0.f;

#pragma unroll 1
    for (int ci = 0; ci < CIN; ci++) {
        const __hip_bfloat16* p = in + (size_t)ci * in_rows * WW + (size_t)(y - in_y0) * WW + xx;
        float v0 = (yl && xl) ? __bfloat162float(p[-WW - 1]) : 0.f;
        float v1 = yl ? __bfloat162float(p[-WW]) : 0.f;
        float v2 = (yl && xh) ? __bfloat162float(p[-WW + 1]) : 0.f;
        float v3 = xl ? __bfloat162float(p[-1]) : 0.f;
        float v4 = __bfloat162float(p[0]);
        float v5 = xh ? __bfloat162float(p[1]) : 0.f;
        float v6 = (yh && xl) ? __bfloat162float(p[WW - 1]) : 0.f;
        float v7 = yh ? __bfloat162float(p[WW]) : 0.f;
        float v8 = (yh && xh) ? __bfloat162float(p[WW + 1]) : 0.f;
#pragma unroll
        for (int c2 = 0; c2 < COUT; c2++) {
            const float* wq = w + (c2 * CIN + ci) * 9;
            acc[c2] = fmaf(v0, wq[0], acc[c2]);
            acc[c2] = fmaf(v1, wq[1], acc[c2]);
            acc[c2] = fmaf(v2, wq[2], acc[c2]);
            acc[c2] = fmaf(v3, wq[3], acc[c2]);
            acc[c2] = fmaf(v4, wq[4], acc[c2]);
            acc[c2] = fmaf(v5, wq[5], acc[c2]);
            acc[c2] = fmaf(v6, wq[6], acc[c2]);
            acc[c2] = fmaf(v7, wq[7], acc[c2]);
            acc[c2] = fmaf(v8, wq[8], acc[c2]);
        }
    }
#pragma unroll
    for (int c = 0; c < COUT; c++) {
        float sc = bg[c] * rsqrtf(bv[c] + 1e-5f);
        float of = bb[c] - bm[c] * sc;
        float r = fmaxf(fmaf(acc[c], sc, of), 0.f);
        out[(size_t)c * out_rows * WW + i] = __float2bfloat16(r);
    }
}

// ---------------------------------------------------------------------------
// final: res(16->3)+tanh, attn(16->1)+sigmoid, combine with xb (f32), clip.
// f3 buffer holds global rows [f3_y0, f3_y0+f3_rows). Writes d_out rows
// [out_y0, out_y0+out_rows) at full-image offsets.
// ---------------------------------------------------------------------------
__global__ __launch_bounds__(256) void final_kernel(
    const __hip_bfloat16* __restrict__ f3, int f3_y0, int f3_rows,
    const float* __restrict__ rw, const float* __restrict__ rb,
    const float* __restrict__ aw, const float* __restrict__ ab,
    const float* __restrict__ xb, const float* __restrict__ stp,
    float* __restrict__ out, int out_y0, int out_rows)
{
    int i = blockIdx.x * blockDim.x + threadIdx.x;
    if (i >= out_rows * WW) return;
    int ly = i / WW;
    int xx = i - ly * WW;
    int y = out_y0 + ly;
    bool yl = y > 0, yh = y < HH - 1, xl = xx > 0, xh = xx < WW - 1;

    float acc[4] = {0.f, 0.f, 0.f, 0.f};

#pragma unroll 1
    for (int ci = 0; ci < 16; ci++) {
        const __hip_bfloat16* p = f3 + (size_t)ci * f3_rows * WW + (size_t)(y - f3_y0) * WW + xx;
        float v0 = (yl && xl) ? __bfloat162float(p[-WW - 1]) : 0.f;
        float v1 = yl ? __bfloat162float(p[-WW]) : 0.f;
        float v2 = (yl && xh) ? __bfloat162float(p[-WW + 1]) : 0.f;
        float v3 = xl ? __bfloat162float(p[-1]) : 0.f;
        float v4 = __bfloat162float(p[0]);
        float v5 = xh ? __bfloat162float(p[1]) : 0.f;
        float v6 = (yh && xl) ? __bfloat162float(p[WW - 1]) : 0.f;
        float v7 = yh ? __bfloat162float(p[WW]) : 0.f;
        float v8 = (yh && xh) ? __bfloat162float(p[WW + 1]) : 0.f;
#pragma unroll
        for (int c2 = 0; c2 < 3; c2++) {
            const float* wq = rw + (c2 * 16 + ci) * 9;
            acc[c2] = fmaf(v0, wq[0], acc[c2]);
            acc[c2] = fmaf(v1, wq[1], acc[c2]);
            acc[c2] = fmaf(v2, wq[2], acc[c2]);
            acc[c2] = fmaf(v3, wq[3], acc[c2]);
            acc[c2] = fmaf(v4, wq[4], acc[c2]);
            acc[c2] = fmaf(v5, wq[5], acc[c2]);
            acc[c2] = fmaf(v6, wq[6], acc[c2]);
            acc[c2] = fmaf(v7, wq[7], acc[c2]);
            acc[c2] = fmaf(v8, wq[8], acc[c2]);
        }
        {
            const float* wq = aw + ci * 9;
            acc[3] = fmaf(v0, wq[0], acc[3]);
            acc[3] = fmaf(v1, wq[1], acc[3]);
            acc[3] = fmaf(v2, wq[2], acc[3]);
            acc[3] = fmaf(v3, wq[3], acc[3]);
            acc[3] = fmaf(v4, wq[4], acc[3]);
            acc[3] = fmaf(v5, wq[5], acc[3]);
            acc[3] = fmaf(v6, wq[6], acc[3]);
            acc[3] = fmaf(v7, wq[7], acc[3]);
            acc[3] = fmaf(v8, wq[8], acc[3]);
        }
    }

    float st = clipf(stp[0], 0.02f, 0.2f);
    float at = 1.f / (1.f + expf(-(acc[3] + ab[0])));
    size_t gi = (size_t)y * WW + xx;
#pragma unroll
    for (int c = 0; c < 3; c++) {
        float rs = tanhf(acc[c] + rb[c]);
        out[(size_t)c * HWSZ + gi] = clipf(xb[(size_t)c * HWSZ + gi] + st * rs * at, 0.f, 1.f);
    }
}

// ---------------------------------------------------------------------------
extern "C" void kernel_launch(void* const* d_in, const int* in_sizes, int n_in,
                              void* d_out, int out_size, void* d_ws, size_t ws_size,
                              hipStream_t stream)
{
    const float* x   = (const float*)d_in[0];
    const float* lut = (const float*)d_in[1];
    const float* cm  = (const float*)d_in[2];
    const float* cb  = (const float*)d_in[3];
    const float* sh  = (const float*)d_in[4];
    const float* mi  = (const float*)d_in[5];
    const float* hi  = (const float*)d_in[6];
    const float* co  = (const float*)d_in[7];
    const float* sa  = (const float*)d_in[8];
    const float* wa  = (const float*)d_in[9];
    const float* lb  = (const float*)d_in[10];
    const float* st  = (const float*)d_in[11];
    const float* w1  = (const float*)d_in[12];
    const float* g1  = (const float*)d_in[13];
    const float* b1  = (const float*)d_in[14];
    const float* m1  = (const float*)d_in[15];
    const float* v1  = (const float*)d_in[16];
    const float* w2  = (const float*)d_in[17];
    const float* g2  = (const float*)d_in[18];
    const float* b2  = (const float*)d_in[19];
    const float* m2  = (const float*)d_in[20];
    const float* v2  = (const float*)d_in[21];
    const float* w3  = (const float*)d_in[22];
    const float* g3  = (const float*)d_in[23];
    const float* b3  = (const float*)d_in[24];
    const float* m3  = (const float*)d_in[25];
    const float* v3  = (const float*)d_in[26];
    const float* rw  = (const float*)d_in[27];
    const float* rb  = (const float*)d_in[28];
    const float* aw  = (const float*)d_in[29];
    const float* ab  = (const float*)d_in[30];

    // Workspace layout (total ~158 MB, fits a 256 MB ws):
    //   xb  : f32, 3 x HWSZ                      = 24.9 MB
    //   f1  : bf16, 32ch x <=544 rows x WW       = 66.8 MB   (f3 aliases f1)
    //   f2  : bf16, 32ch x <=544 rows x WW       = 66.8 MB
    char* ws = (char*)d_ws;
    const size_t XB_BYTES = (size_t)3 * HWSZ * sizeof(float);
    const size_t F_BYTES  = (size_t)32 * 544 * WW * sizeof(__hip_bfloat16);
    float* xb = (float*)ws;
    __hip_bfloat16* f1 = (__hip_bfloat16*)(ws + XB_BYTES);
    __hip_bfloat16* f2 = (__hip_bfloat16*)(ws + XB_BYTES + F_BYTES);
    __hip_bfloat16* f3 = f1;  // f1 dead once conv2 of this half is done

    {
        int grid = (HWSZ + 255) / 256;
        grade_kernel<<<grid, 256, 0, stream>>>(x, lut, cm, cb, sh, mi, hi, co, sa, wa, lb, xb);
    }

    // Two horizontal halves with exact halo recomputation.
    // Half h produces output rows [r0, r1). Halos: f3 needs +-1, f2 +-2, f1 +-3.
    for (int h = 0; h < 2; h++) {
        int r0 = (h == 0) ? 0 : HH / 2;
        int r1 = (h == 0) ? HH / 2 : HH;

        int f1_y0 = max(r0 - 3, 0), f1_y1 = min(r1 + 3, HH);
        int f2_y0 = max(r0 - 2, 0), f2_y1 = min(r1 + 2, HH);
        int f3_y0 = max(r0 - 1, 0), f3_y1 = min(r1 + 1, HH);
        int f1_rows = f1_y1 - f1_y0;
        int f2_rows = f2_y1 - f2_y0;
        int f3_rows = f3_y1 - f3_y0;
        int out_rows = r1 - r0;

        int g1r = (f1_rows * WW + 255) / 256;
        int g2r = (f2_rows * WW + 255) / 256;
        int g3r = (f3_rows * WW + 255) / 256;
        int g4r = (out_rows * WW + 255) / 256;

        conv1_kernel<<<g1r, 256, 0, stream>>>(x, xb, w1, g1, b1, m1, v1,
                                              f1, f1_y0, f1_rows);
        conv_bn_relu_bf16<32, 32><<<g2r, 256, 0, stream>>>(f1, f1_y0, f1_rows,
                                                           w2, g2, b2, m2, v2,
                                                           f2, f2_y0, f2_rows);
        conv_bn_relu_bf16<32, 16><<<g3r, 256, 0, stream>>>(f2, f2_y0, f2_rows,
                                                           w3, g3, b3, m3, v3,
                                                           f3, f3_y0, f3_rows);
        final_kernel<<<g4r, 256, 0, stream>>>(f3, f3_y0, f3_rows,
                                              rw, rb, aw, ab, xb, st,
                                              (float*)d_out, r0, out_rows);
    }
}

// Round 3
// 502.463 us; speedup vs baseline: 3.2484x; 3.2484x over previous
//
#include <hip/hip_runtime.h>
#include <hip/hip_bf16.h>

#define HH 1080
#define WW 1920
#define HWSZ (HH * WW)

typedef __attribute__((ext_vector_type(8))) short bf16x8;
typedef __attribute__((ext_vector_type(4))) float f32x4;
typedef __attribute__((ext_vector_type(4))) short s16x4;

__device__ __forceinline__ float clipf(float x, float lo, float hi) {
    return fminf(fmaxf(x, lo), hi);
}
__device__ __forceinline__ short f2bf(float f) {
    __hip_bfloat16 h = __float2bfloat16(f);
    return *(short*)&h;
}
__device__ __forceinline__ float fpow(float a, float e) {
    return __expf(__logf(a) * e);   // a >= 1e-7 guaranteed by callers
}

// ---------------------------------------------------------------------------
// Kernel 1: classical grade + 3D LUT + blend.
// Writes: xb (planar f32, for the final blend) and xin (NHWC bf16, 8 ch:
// [x0,x1,x2, xb0,xb1,xb2, 0,0]) as conv1 input.
// ---------------------------------------------------------------------------
__global__ __launch_bounds__(256) void grade_kernel(
    const float* __restrict__ x, const float* __restrict__ lut,
    const float* __restrict__ cm, const float* __restrict__ cbp,
    const float* __restrict__ shp, const float* __restrict__ mip,
    const float* __restrict__ hip_, const float* __restrict__ cop,
    const float* __restrict__ satp, const float* __restrict__ wap,
    const float* __restrict__ lbp,
    float* __restrict__ xb, __hip_bfloat16* __restrict__ xin)
{
    int i = blockIdx.x * blockDim.x + threadIdx.x;
    if (i >= HWSZ) return;

    float in0 = x[i], in1 = x[HWSZ + i], in2 = x[2 * HWSZ + i];

    float M00 = clipf(cm[0], 0.9f, 1.1f), M01 = clipf(cm[1], 0.9f, 1.1f), M02 = clipf(cm[2], 0.9f, 1.1f);
    float M10 = clipf(cm[3], 0.9f, 1.1f), M11 = clipf(cm[4], 0.9f, 1.1f), M12 = clipf(cm[5], 0.9f, 1.1f);
    float M20 = clipf(cm[6], 0.9f, 1.1f), M21 = clipf(cm[7], 0.9f, 1.1f), M22 = clipf(cm[8], 0.9f, 1.1f);
    float bi0 = clipf(cbp[0], -0.02f, 0.02f);
    float bi1 = clipf(cbp[1], -0.02f, 0.02f);
    float bi2 = clipf(cbp[2], -0.02f, 0.02f);

    float sh  = clipf(shp[0], -0.02f, 0.05f);
    float mi  = clipf(mip[0], 0.95f, 1.05f);
    float hi  = clipf(hip_[0], 0.95f, 1.05f);
    float co  = clipf(cop[0], 0.98f, 1.05f);
    float sat = clipf(satp[0], 0.95f, 1.3f);
    float wa  = clipf(wap[0], -0.02f, 0.05f);
    float lb  = clipf(lbp[0], 0.7f, 0.9f);

    float xc[3];
    xc[0] = M00 * in0 + M01 * in1 + M02 * in2 + bi0;
    xc[1] = M10 * in0 + M11 * in1 + M12 * in2 + bi1;
    xc[2] = M20 * in0 + M21 * in1 + M22 * in2 + bi2;

    float inv_mi = 1.0f / mi, inv_co = 1.0f / co;
    float xg[3];
#pragma unroll
    for (int c = 0; c < 3; c++) {
        float v = xc[c];
        float sm = clipf(1.f - v, 0.f, 1.f);
        sm = sm * sm * sm;
        float xs = v + sh * sm * (1.f - v) * 0.5f;
        float xm = fpow(clipf(xs, 1e-7f, 1.f), inv_mi);
        float hm = clipf(xm, 0.f, 1.f);
        hm = hm * hm * hm;
        float x2 = clipf(xm * (1.f - hm * (1.f - hi) * 0.5f), 0.f, 1.f);
        xg[c] = fpow(clipf(x2, 1e-7f, 1.f), inv_co);
    }

    float luma = 0.299f * xg[0] + 0.587f * xg[1] + 0.114f * xg[2];
    float s0 = luma + sat * (xg[0] - luma);
    float s1 = luma + sat * (xg[1] - luma);
    float s2 = luma + sat * (xg[2] - luma);

    float pr = clipf(s0 * (1.f + wa), 0.f, 1.f);
    float pg = clipf(s1 * (1.f + wa * 0.3f), 0.f, 1.f);
    float pb = clipf(s2 * (1.f - wa * 0.5f), 0.f, 1.f);

    float cr = pr * 32.f, cg = pg * 32.f, cb2 = pb * 32.f;
    float fr = floorf(cr), fgq = floorf(cg), fb = floorf(cb2);
    float fx = cr - fr, fy = cg - fgq, fz = cb2 - fb;
    int x0 = min(max((int)fr, 0), 31);
    int y0 = min(max((int)fgq, 0), 31);
    int z0 = min(max((int)fb, 0), 31);

    const float* base = lut + ((x0 * 33 + y0) * 33 + z0) * 3;
    float pcl[3] = {pr, pg, pb};
    float bl[3];
#pragma unroll
    for (int ch = 0; ch < 3; ch++) {
        float c000 = base[ch];
        float c001 = base[3 + ch];
        float c010 = base[99 + ch];
        float c011 = base[102 + ch];
        float c100 = base[3267 + ch];
        float c101 = base[3270 + ch];
        float c110 = base[3366 + ch];
        float c111 = base[3369 + ch];
        float c00 = c000 * (1.f - fx) + c100 * fx;
        float c01 = c001 * (1.f - fx) + c101 * fx;
        float c10 = c010 * (1.f - fx) + c110 * fx;
        float c11 = c011 * (1.f - fx) + c111 * fx;
        float c0 = c00 * (1.f - fy) + c10 * fy;
        float c1 = c01 * (1.f - fy) + c11 * fy;
        float lv = c0 * (1.f - fz) + c1 * fz;
        bl[ch] = lb * lv + (1.f - lb) * pcl[ch];
        xb[(size_t)ch * HWSZ + i] = bl[ch];
    }

    bf16x8 xi;
    xi[0] = f2bf(in0); xi[1] = f2bf(in1); xi[2] = f2bf(in2);
    xi[3] = f2bf(bl[0]); xi[4] = f2bf(bl[1]); xi[5] = f2bf(bl[2]);
    xi[6] = 0; xi[7] = 0;
    *(bf16x8*)(xin + (size_t)i * 8) = xi;
}

// ---------------------------------------------------------------------------
// Implicit-GEMM MFMA conv, NHWC bf16. K ordered tap-major: k = tap*CI + ci.
// mfma_f32_16x16x32_bf16: A lane l holds rowM=l&15, k=(l>>4)*8+j.
//                         B lane l holds colN=l&15 (pixel), same k slots.
//                         D lane l holds colN=l&15, rowM=(l>>4)*4+reg.
// BN scale folded into weights; BN offset (or conv bias) folded into acc init.
// Each wave: one output row, 384-px segment = 24 tiles of 16 pixels.
// FINAL: COUT rows 0-2 = res, row 3 = attn; epilogue on sub==0 lanes does
// tanh/sigmoid + blend with xb and writes planar f32 d_out.
// ---------------------------------------------------------------------------
template <int CI, int CIR, int COUTB, int COUTR, int NG, bool FINAL>
__global__ __launch_bounds__(256) void conv_mfma(
    const __hip_bfloat16* __restrict__ in, int in_y0, int in_rows,
    const float* __restrict__ w, const float* __restrict__ w2,
    const float* __restrict__ bg, const float* __restrict__ bb,
    const float* __restrict__ bm, const float* __restrict__ bv,
    __hip_bfloat16* __restrict__ out, int out_y0, int out_rows,
    const float* __restrict__ xb, const float* __restrict__ stp,
    float* __restrict__ fout)
{
    constexpr int COUT = COUTB * 16;
    constexpr int SEGW = 384;

    int l   = threadIdx.x & 63;
    int wv  = threadIdx.x >> 6;
    int lrow = blockIdx.y * 4 + wv;
    if (lrow >= out_rows) return;
    int y  = out_y0 + lrow;
    int x0 = blockIdx.x * SEGW;
    int mrow = l & 15;
    int sub  = l >> 4;

    // Accumulator init: BN offset (or bias), per output row held by this lane.
    f32x4 ainit[COUTB];
#pragma unroll
    for (int cb = 0; cb < COUTB; cb++) {
#pragma unroll
        for (int r = 0; r < 4; r++) {
            int c = cb * 16 + sub * 4 + r;
            float v = 0.f;
            if (FINAL) {
                v = (c < 3) ? bb[c] : (c == 3 ? bm[0] : 0.f);
            } else if (c < COUTR) {
                float s = bg[c] * rsqrtf(bv[c] + 1e-5f);
                v = bb[c] - bm[c] * s;
            }
            ainit[cb][r] = v;
        }
    }

    // Weight fragments (BN scale folded). Per lane: rowM = cb*16+mrow.
    bf16x8 wf[COUTB][NG];
#pragma unroll
    for (int cb = 0; cb < COUTB; cb++) {
        int cout = cb * 16 + mrow;
        float scl = 1.f;
        if (!FINAL)
            scl = (cout < COUTR) ? bg[cout] * rsqrtf(bv[cout] + 1e-5f) : 0.f;
#pragma unroll
        for (int g = 0; g < NG; g++) {
            bf16x8 f;
#pragma unroll
            for (int j = 0; j < 8; j++) {
                int k  = g * 32 + sub * 8 + j;
                int tap = k / CI;
                int ci  = k % CI;
                float val = 0.f;
                if (tap < 9 && ci < CIR && cout < COUTR) {
                    if (FINAL)
                        val = (cout < 3) ? w[(cout * CIR + ci) * 9 + tap]
                                         : w2[ci * 9 + tap];
                    else
                        val = w[(cout * CIR + ci) * 9 + tap] * scl;
                }
                f[j] = f2bf(val);
            }
            wf[cb][g] = f;
        }
    }

    // Per-group geometry (fixed per lane for whole kernel).
    const __hip_bfloat16* baseg[NG];
    int dxg[NG];
    bool okg[NG];
#pragma unroll
    for (int g = 0; g < NG; g++) {
        int kl  = g * 32 + sub * 8;
        int tap = kl / CI;
        int cib = kl % CI;
        int dy = (tap < 9) ? tap / 3 - 1 : 0;
        int dx = (tap < 9) ? tap % 3 - 1 : 0;
        int yy = y + dy;
        okg[g] = (yy >= 0 && yy < HH);
        baseg[g] = in + ((long)(yy - in_y0) * WW + dx) * CI + cib;
        dxg[g] = dx;
    }

    for (int t = 0; t < SEGW / 16; t++) {
        int xp = x0 + t * 16 + mrow;   // this lane's pixel column (B and D)

        bf16x8 bfr[NG];
#pragma unroll
        for (int g = 0; g < NG; g++) {
            int xx = xp + dxg[g];
            bf16x8 v = {0, 0, 0, 0, 0, 0, 0, 0};
            if (okg[g] && (unsigned)xx < (unsigned)WW)
                v = *(const bf16x8*)(baseg[g] + (size_t)xp * CI);
            bfr[g] = v;
        }

        f32x4 acc[COUTB];
#pragma unroll
        for (int cb = 0; cb < COUTB; cb++) acc[cb] = ainit[cb];
#pragma unroll
        for (int g = 0; g < NG; g++) {
#pragma unroll
            for (int cb = 0; cb < COUTB; cb++)
                acc[cb] = __builtin_amdgcn_mfma_f32_16x16x32_bf16(
                    wf[cb][g], bfr[g], acc[cb], 0, 0, 0);
        }

        if constexpr (!FINAL) {
#pragma unroll
            for (int cb = 0; cb < COUTB; cb++) {
                s16x4 s;
#pragma unroll
                for (int r = 0; r < 4; r++) s[r] = f2bf(fmaxf(acc[cb][r], 0.f));
                *(s16x4*)(out + ((size_t)lrow * WW + xp) * COUT + cb * 16 + sub * 4) = s;
            }
        } else {
            if (sub == 0) {
                float st = clipf(stp[0], 0.02f, 0.2f);
                float at = 1.f / (1.f + __expf(-acc[0][3]));
                size_t gi = (size_t)y * WW + xp;
#pragma unroll
                for (int c = 0; c < 3; c++) {
                    float rs = tanhf(acc[0][c]);
                    fout[(size_t)c * HWSZ + gi] =
                        clipf(xb[(size_t)c * HWSZ + gi] + st * rs * at, 0.f, 1.f);
                }
            }
        }
    }
}

// ---------------------------------------------------------------------------
extern "C" void kernel_launch(void* const* d_in, const int* in_sizes, int n_in,
                              void* d_out, int out_size, void* d_ws, size_t ws_size,
                              hipStream_t stream)
{
    const float* x   = (const float*)d_in[0];
    const float* lut = (const float*)d_in[1];
    const float* cm  = (const float*)d_in[2];
    const float* cb  = (const float*)d_in[3];
    const float* sh  = (const float*)d_in[4];
    const float* mi  = (const float*)d_in[5];
    const float* hi  = (const float*)d_in[6];
    const float* co  = (const float*)d_in[7];
    const float* sa  = (const float*)d_in[8];
    const float* wa  = (const float*)d_in[9];
    const float* lb  = (const float*)d_in[10];
    const float* st  = (const float*)d_in[11];
    const float* w1  = (const float*)d_in[12];
    const float* g1  = (const float*)d_in[13];
    const float* b1  = (const float*)d_in[14];
    const float* m1  = (const float*)d_in[15];
    const float* v1  = (const float*)d_in[16];
    const float* w2  = (const float*)d_in[17];
    const float* g2  = (const float*)d_in[18];
    const float* b2  = (const float*)d_in[19];
    const float* m2  = (const float*)d_in[20];
    const float* v2  = (const float*)d_in[21];
    const float* w3  = (const float*)d_in[22];
    const float* g3  = (const float*)d_in[23];
    const float* b3  = (const float*)d_in[24];
    const float* m3  = (const float*)d_in[25];
    const float* v3  = (const float*)d_in[26];
    const float* rw  = (const float*)d_in[27];
    const float* rb  = (const float*)d_in[28];
    const float* aw  = (const float*)d_in[29];
    const float* ab  = (const float*)d_in[30];

    // Workspace (~192 MB):
    //   xb  : planar f32, 3*HWSZ                    = 24.9 MB
    //   xin : NHWC bf16, 8ch full image             = 33.2 MB
    //   f1  : NHWC bf16, 32ch x <=543 rows          = 66.7 MB   (f3 aliases)
    //   f2  : NHWC bf16, 32ch x <=543 rows          = 66.7 MB
    char* ws = (char*)d_ws;
    const size_t XB_BYTES  = (size_t)3 * HWSZ * sizeof(float);
    const size_t XIN_BYTES = (size_t)8 * HWSZ * sizeof(__hip_bfloat16);
    const size_t F_BYTES   = (size_t)32 * 543 * WW * sizeof(__hip_bfloat16);
    float* xb = (float*)ws;
    __hip_bfloat16* xin = (__hip_bfloat16*)(ws + XB_BYTES);
    __hip_bfloat16* f1  = (__hip_bfloat16*)(ws + XB_BYTES + XIN_BYTES);
    __hip_bfloat16* f2  = (__hip_bfloat16*)(ws + XB_BYTES + XIN_BYTES + F_BYTES);
    __hip_bfloat16* f3  = f1;   // f1 dead once conv2 of this half is done

    {
        int grid = (HWSZ + 255) / 256;
        grade_kernel<<<grid, 256, 0, stream>>>(x, lut, cm, cb, sh, mi, hi, co,
                                               sa, wa, lb, xb, xin);
    }

    for (int h = 0; h < 2; h++) {
        int r0 = (h == 0) ? 0 : HH / 2;
        int r1 = (h == 0) ? HH / 2 : HH;

        int f1_y0 = max(r0 - 3, 0), f1_y1 = min(r1 + 3, HH);
        int f2_y0 = max(r0 - 2, 0), f2_y1 = min(r1 + 2, HH);
        int f3_y0 = max(r0 - 1, 0), f3_y1 = min(r1 + 1, HH);
        int f1_rows = f1_y1 - f1_y0;
        int f2_rows = f2_y1 - f2_y0;
        int f3_rows = f3_y1 - f3_y0;
        int out_rows = r1 - r0;

        dim3 blk(256);
        dim3 gr1(5, (f1_rows + 3) / 4);
        dim3 gr2(5, (f2_rows + 3) / 4);
        dim3 gr3(5, (f3_rows + 3) / 4);
        dim3 gr4(5, (out_rows + 3) / 4);

        // conv1: 6(->8 padded) -> 32, K=96 (12 taps, 3 zero)
        conv_mfma<8, 6, 2, 32, 3, false><<<gr1, blk, 0, stream>>>(
            xin, 0, HH, w1, nullptr, g1, b1, m1, v1,
            f1, f1_y0, f1_rows, nullptr, nullptr, nullptr);
        // conv2: 32 -> 32, K=288
        conv_mfma<32, 32, 2, 32, 9, false><<<gr2, blk, 0, stream>>>(
            f1, f1_y0, f1_rows, w2, nullptr, g2, b2, m2, v2,
            f2, f2_y0, f2_rows, nullptr, nullptr, nullptr);
        // conv3: 32 -> 16, K=288
        conv_mfma<32, 32, 1, 16, 9, false><<<gr3, blk, 0, stream>>>(
            f2, f2_y0, f2_rows, w3, nullptr, g3, b3, m3, v3,
            f3, f3_y0, f3_rows, nullptr, nullptr, nullptr);
        // final: 16 -> 4 (res0-2 + attn), K=160 (10 taps, 1 zero), fused blend
        conv_mfma<16, 16, 1, 4, 5, true><<<gr4, blk, 0, stream>>>(
            f3, f3_y0, f3_rows, rw, aw, rb, rb, ab, ab,
            nullptr, r0, out_rows, xb, st, (float*)d_out);
    }
}